// Round 5
// baseline (182.978 us; speedup 1.0000x reference)
//
#include <hip/hip_runtime.h>

typedef __attribute__((ext_vector_type(8))) short s16x8;
typedef __attribute__((ext_vector_type(4))) short s16x4;
typedef __attribute__((ext_vector_type(4))) float fx4;

__device__ inline unsigned short f2bf(float f) {
  unsigned u = __float_as_uint(f);
  u += 0x7fffu + ((u >> 16) & 1u);
  return (unsigned short)(u >> 16);
}
__device__ inline float bf2f(unsigned short s) {
  return __uint_as_float(((unsigned)s) << 16);
}

#define GLDS16(gp, lp) \
  __builtin_amdgcn_global_load_lds((const __attribute__((address_space(1))) void*)(gp), \
                                   (__attribute__((address_space(3))) void*)(lp), 16, 0, 0)

// ---------------- cast / transpose kernels ----------------
__global__ __launch_bounds__(256) void cast_x_k(const float* __restrict__ x,
                                                unsigned short* __restrict__ xb) {
  int i = (blockIdx.x * 256 + threadIdx.x) * 8;
  fx4 a = *(const fx4*)&x[i];
  fx4 b = *(const fx4*)&x[i + 4];
  s16x8 o;
  o[0] = (short)f2bf(a[0]); o[1] = (short)f2bf(a[1]);
  o[2] = (short)f2bf(a[2]); o[3] = (short)f2bf(a[3]);
  o[4] = (short)f2bf(b[0]); o[5] = (short)f2bf(b[1]);
  o[6] = (short)f2bf(b[2]); o[7] = (short)f2bf(b[3]);
  *(s16x8*)&xb[i] = o;
}

__global__ __launch_bounds__(256) void twqkv_k(const float* __restrict__ w,
                                               unsigned short* __restrict__ wT) {
  int o = blockIdx.x * 256 + threadIdx.x;      // < 1536*512
  int j = o >> 9, kk = o & 511;
  wT[o] = f2bf(w[kk * 1536 + j]);
}

__global__ __launch_bounds__(256) void cast_wp_k(const float* __restrict__ w,
                                                 unsigned short* __restrict__ wb) {
  int o = blockIdx.x * 256 + threadIdx.x;      // < 512*512
  wb[o] = f2bf(w[o]);
}

// ---------------- GEMM: 256x256 tile, BK=64, 8 waves (2Mx4N), 8-phase-style
// schedule: per K-tile 4 phases x 16 MFMA (quadrants qm x ks), staging of tile
// t+1 issued at phases 0/1 of tile t, ONE counted vmcnt(4) per K-tile, raw
// s_barrier (no implicit drain), setprio around MFMA clusters (T5).
// LDS 128 KiB dbuf. Chunk-XOR swizzle slot = chunk ^ (row&7): conflict-free
// (8 chunks per bank-group per wave b128 read). Linear GLDS dest + inverse-
// swizzled global source + swizzled read (rule 21).
// MODE 0: A=[32768][512] xb, BT=[1536][512] wqkvT -> q,k,v (bf16 split layouts)
// MODE 1: A=v + bb*4096*512, BT=weffT + bb*512*512 -> fp32 [b n][512]
template <int MODE>
__global__ __launch_bounds__(512, 2) void gemm_k(
    const unsigned short* __restrict__ A, const unsigned short* __restrict__ BT,
    const float* __restrict__ bias,
    unsigned short* __restrict__ qo, unsigned short* __restrict__ ko,
    unsigned short* __restrict__ vo, float* __restrict__ outp) {
  __shared__ alignas(16) unsigned short As[2][16384];   // [buf][256 rows x 64 k]
  __shared__ alignas(16) unsigned short Bs[2][16384];
  int tid = threadIdx.x, wave = tid >> 6, lane = tid & 63;
  int l15 = lane & 15, l16 = lane >> 4;
  int wr = wave >> 2, wc = wave & 3;   // 2 x 4 wave grid

  // XCD-aware bijective swizzle (nwg % 8 == 0 in both modes)
  int nwg = (MODE == 0) ? 768 : 256;
  int cpx = nwg >> 3;
  int bid = (blockIdx.x & 7) * cpx + (blockIdx.x >> 3);

  int mt, nt, bb = 0;
  if (MODE == 0) { mt = bid / 6; nt = bid % 6; }
  else { bb = bid >> 5; int r = bid & 31; mt = r >> 1; nt = r & 1; }
  const unsigned short* Ab = A + (MODE == 0 ? (size_t)0 : (size_t)bb * 4096 * 512);
  const unsigned short* Bb = BT + (MODE == 0 ? (size_t)0 : (size_t)bb * 512 * 512);
  int row0 = mt * 256, col0 = nt * 256;

  fx4 acc[8][4];
#pragma unroll
  for (int i = 0; i < 8; ++i)
#pragma unroll
    for (int j = 0; j < 4; ++j) acc[i][j] = (fx4){0.f, 0.f, 0.f, 0.f};

  // Staging: per glds call, 512 lanes x 16B = 64 rows x 128B. Lane's global
  // source chunk is pre-swizzled by row&7 so linear LDS dest yields
  // stored slot p = chunk ^ (row&7).
  int srow = tid >> 3;                                  // row within 64-row call
  int sch = ((tid & 7) ^ ((tid >> 3) & 7)) * 8;         // swizzled src chunk
  const unsigned short* agp = Ab + (size_t)(row0 + srow) * 512 + sch;
  const unsigned short* bgp = Bb + (size_t)(col0 + srow) * 512 + sch;
  int wofs = wave * 512;

#define SGA(buf, t, c) GLDS16(agp + (size_t)(c) * 32768 + (t) * 64, &As[buf][(c) * 4096 + wofs])
#define SGB(buf, t, c) GLDS16(bgp + (size_t)(c) * 32768 + (t) * 64, &Bs[buf][(c) * 4096 + wofs])

  // read-side swizzle: slot = (ks*4 + l16) ^ (l15&7); elem ofs = slot*8.
  int swof0 = (l16 ^ (l15 & 7)) * 8;                    // ks=0; ks=1 is ^32

  s16x8 bf0, bf1, bf2, bf3;

#define PHASE(bufi, qm, ks, RB)                                                                   \
  do {                                                                                            \
    const unsigned short* Ap_ = &As[bufi][(wr * 128 + (qm) * 64 + l15) * 64 + (swof0 ^ ((ks) * 32))]; \
    const unsigned short* Bp_ = &Bs[bufi][(wc * 64 + l15) * 64 + (swof0 ^ ((ks) * 32))];          \
    if (RB) {                                                                                     \
      bf0 = *(const s16x8*)&Bp_[0];                                                               \
      bf1 = *(const s16x8*)&Bp_[1024];                                                            \
      bf2 = *(const s16x8*)&Bp_[2048];                                                            \
      bf3 = *(const s16x8*)&Bp_[3072];                                                            \
    }                                                                                             \
    s16x8 af0 = *(const s16x8*)&Ap_[0];                                                           \
    s16x8 af1 = *(const s16x8*)&Ap_[1024];                                                        \
    s16x8 af2 = *(const s16x8*)&Ap_[2048];                                                        \
    s16x8 af3 = *(const s16x8*)&Ap_[3072];                                                        \
    __builtin_amdgcn_s_setprio(1);                                                                \
    acc[(qm)*4+0][0] = __builtin_amdgcn_mfma_f32_16x16x32_bf16(af0, bf0, acc[(qm)*4+0][0],0,0,0); \
    acc[(qm)*4+0][1] = __builtin_amdgcn_mfma_f32_16x16x32_bf16(af0, bf1, acc[(qm)*4+0][1],0,0,0); \
    acc[(qm)*4+0][2] = __builtin_amdgcn_mfma_f32_16x16x32_bf16(af0, bf2, acc[(qm)*4+0][2],0,0,0); \
    acc[(qm)*4+0][3] = __builtin_amdgcn_mfma_f32_16x16x32_bf16(af0, bf3, acc[(qm)*4+0][3],0,0,0); \
    acc[(qm)*4+1][0] = __builtin_amdgcn_mfma_f32_16x16x32_bf16(af1, bf0, acc[(qm)*4+1][0],0,0,0); \
    acc[(qm)*4+1][1] = __builtin_amdgcn_mfma_f32_16x16x32_bf16(af1, bf1, acc[(qm)*4+1][1],0,0,0); \
    acc[(qm)*4+1][2] = __builtin_amdgcn_mfma_f32_16x16x32_bf16(af1, bf2, acc[(qm)*4+1][2],0,0,0); \
    acc[(qm)*4+1][3] = __builtin_amdgcn_mfma_f32_16x16x32_bf16(af1, bf3, acc[(qm)*4+1][3],0,0,0); \
    acc[(qm)*4+2][0] = __builtin_amdgcn_mfma_f32_16x16x32_bf16(af2, bf0, acc[(qm)*4+2][0],0,0,0); \
    acc[(qm)*4+2][1] = __builtin_amdgcn_mfma_f32_16x16x32_bf16(af2, bf1, acc[(qm)*4+2][1],0,0,0); \
    acc[(qm)*4+2][2] = __builtin_amdgcn_mfma_f32_16x16x32_bf16(af2, bf2, acc[(qm)*4+2][2],0,0,0); \
    acc[(qm)*4+2][3] = __builtin_amdgcn_mfma_f32_16x16x32_bf16(af2, bf3, acc[(qm)*4+2][3],0,0,0); \
    acc[(qm)*4+3][0] = __builtin_amdgcn_mfma_f32_16x16x32_bf16(af3, bf0, acc[(qm)*4+3][0],0,0,0); \
    acc[(qm)*4+3][1] = __builtin_amdgcn_mfma_f32_16x16x32_bf16(af3, bf1, acc[(qm)*4+3][1],0,0,0); \
    acc[(qm)*4+3][2] = __builtin_amdgcn_mfma_f32_16x16x32_bf16(af3, bf2, acc[(qm)*4+3][2],0,0,0); \
    acc[(qm)*4+3][3] = __builtin_amdgcn_mfma_f32_16x16x32_bf16(af3, bf3, acc[(qm)*4+3][3],0,0,0); \
    __builtin_amdgcn_s_setprio(0);                                                                \
    asm volatile("s_barrier" ::: "memory");                                                       \
  } while (0)

  // prologue: stage K-tile 0 into buf0 (8 loads)
  SGA(0, 0, 0); SGA(0, 0, 1); SGA(0, 0, 2); SGA(0, 0, 3);
  SGB(0, 0, 0); SGB(0, 0, 1); SGB(0, 0, 2); SGB(0, 0, 3);

  for (int t = 0; t < 7; ++t) {
    int buf = t & 1, nbuf = buf ^ 1;
    // ph0: issue next-tile A (4 loads), drain current tile (keep 4), sync
    SGA(nbuf, t + 1, 0); SGA(nbuf, t + 1, 1); SGA(nbuf, t + 1, 2); SGA(nbuf, t + 1, 3);
    asm volatile("s_waitcnt vmcnt(4)" ::: "memory");
    asm volatile("s_barrier" ::: "memory");
    PHASE(buf, 0, 0, true);
    // ph1: issue next-tile B (4 loads)
    SGB(nbuf, t + 1, 0); SGB(nbuf, t + 1, 1); SGB(nbuf, t + 1, 2); SGB(nbuf, t + 1, 3);
    PHASE(buf, 1, 0, false);
    // ph2 / ph3
    PHASE(buf, 0, 1, true);
    PHASE(buf, 1, 1, false);
  }
  // tail: K-tile 7 in buf1, nothing left to stage
  asm volatile("s_waitcnt vmcnt(0)" ::: "memory");
  asm volatile("s_barrier" ::: "memory");
  PHASE(1, 0, 0, true);
  PHASE(1, 1, 0, false);
  PHASE(1, 0, 1, true);
  PHASE(1, 1, 1, false);
#undef PHASE
#undef SGA
#undef SGB

  int crow0 = row0 + wr * 128;
  int ccol0 = col0 + wc * 64;
  if (MODE == 0) {
    int seg = col0 >> 9;  // 0=q,1=k,2=v (256-tile never spans 512-segments)
#pragma unroll
    for (int am = 0; am < 8; ++am)
#pragma unroll
      for (int nj = 0; nj < 4; ++nj) {
        int gc = ccol0 + nj * 16 + l15;
        float bsv = bias[gc];
#pragma unroll
        for (int r = 0; r < 4; ++r) {
          int gr = crow0 + am * 16 + l16 * 4 + r;
          unsigned short o = f2bf(acc[am][nj][r] + bsv);
          int b_ = gr >> 12, n_ = gr & 4095;
          if (seg == 0) {
            qo[((((size_t)b_ * 8 + (gc >> 6)) * 4096 + n_) << 6) + (gc & 63)] = o;
          } else if (seg == 1) {
            int c2 = gc - 512;
            ko[((((size_t)b_ * 8 + (c2 >> 6)) * 4096 + n_) << 6) + (c2 & 63)] = o;
          } else {
            vo[((size_t)gr << 9) + (gc - 1024)] = o;
          }
        }
      }
  } else {
#pragma unroll
    for (int am = 0; am < 8; ++am)
#pragma unroll
      for (int nj = 0; nj < 4; ++nj) {
        int gc = ccol0 + nj * 16 + l15;
        float bsv = bias[gc];
#pragma unroll
        for (int r = 0; r < 4; ++r) {
          int gr = crow0 + am * 16 + l16 * 4 + r;  // row within batch
          outp[(((size_t)bb * 4096 + gr) << 9) + gc] = acc[am][nj][r] + bsv;
        }
      }
  }
}

// ---------------- partial scores: S_part[bh][seg][d][e] = sum_{n in seg} q[n][d]*k[n][e]
__global__ __launch_bounds__(256) void scores_partial_k(const unsigned short* __restrict__ q,
                                                        const unsigned short* __restrict__ k,
                                                        float* __restrict__ sp) {
  __shared__ alignas(16) float qs[64 * 64];
  __shared__ alignas(16) float ks[64 * 64];
  int bid = blockIdx.x;            // 512 = bh*8 + seg
  int bh = bid >> 3, seg = bid & 7;
  const unsigned short* qb = q + ((size_t)bh * 4096 + seg * 512) * 64;
  const unsigned short* kb = k + ((size_t)bh * 4096 + seg * 512) * 64;
  int tid = threadIdx.x;
  int dg = tid >> 4, eg = tid & 15;
  float acc[4][4] = {{0.f}};
  for (int ch = 0; ch < 8; ++ch) {
    __syncthreads();
    for (int r = 0; r < 4; ++r) {
      int idx = r * 1024 + tid * 4;
      s16x4 qv = *(const s16x4*)&qb[ch * 4096 + idx];
      s16x4 kv = *(const s16x4*)&kb[ch * 4096 + idx];
      fx4 qf = {bf2f((unsigned short)qv[0]), bf2f((unsigned short)qv[1]),
                bf2f((unsigned short)qv[2]), bf2f((unsigned short)qv[3])};
      fx4 kf = {bf2f((unsigned short)kv[0]), bf2f((unsigned short)kv[1]),
                bf2f((unsigned short)kv[2]), bf2f((unsigned short)kv[3])};
      *(fx4*)&qs[idx] = qf;
      *(fx4*)&ks[idx] = kf;
    }
    __syncthreads();
    for (int n = 0; n < 64; ++n) {
      fx4 qv4 = *(const fx4*)&qs[n * 64 + dg * 4];
      fx4 kv4 = *(const fx4*)&ks[n * 64 + eg * 4];
      for (int i = 0; i < 4; ++i)
        for (int j = 0; j < 4; ++j) acc[i][j] += qv4[i] * kv4[j];
    }
  }
  float* o = sp + (size_t)bid * 4096;
  for (int i = 0; i < 4; ++i)
    for (int j = 0; j < 4; ++j) o[(dg * 4 + i) * 64 + eg * 4 + j] = acc[i][j];
}

// ---------------- softmax + W_effT[b][j][h*64+e] = sum_d attn[d][e] * wp[h*64+d][j]
// grid 256: block = bh*4 + jblk, each handles 128 output j-columns
__global__ __launch_bounds__(256) void softmax_weff_k(const float* __restrict__ sp,
                                                      const unsigned short* __restrict__ wpb,
                                                      const float* __restrict__ temp,
                                                      unsigned short* __restrict__ weffT) {
  __shared__ alignas(16) float S[64 * 64];
  __shared__ alignas(16) unsigned short wps[64 * 128];
  int bh = blockIdx.x >> 2, jblk = blockIdx.x & 3;
  int b = bh >> 3, h = bh & 7;
  int tid = threadIdx.x;
  float tval = temp[h];
  for (int i = tid * 4; i < 4096; i += 1024) {
    fx4 s = {0.f, 0.f, 0.f, 0.f};
    for (int seg = 0; seg < 8; ++seg) {
      fx4 v4 = *(const fx4*)&sp[((size_t)(bh * 8 + seg)) * 4096 + i];
      s += v4;
    }
    s *= tval;
    *(fx4*)&S[i] = s;
  }
  // stage wp slice: rows h*64..h*64+63, cols jblk*128..+128
  for (int i = tid * 8; i < 8192; i += 2048) {
    int d = i >> 7, c = i & 127;
    *(s16x8*)&wps[i] = *(const s16x8*)&wpb[(size_t)(h * 64 + d) * 512 + jblk * 128 + c];
  }
  __syncthreads();
  if (tid < 64) {
    float* row = &S[tid * 64];
    float mx = row[0];
    for (int e = 1; e < 64; ++e) mx = fmaxf(mx, row[e]);
    float sum = 0.f;
    for (int e = 0; e < 64; ++e) { float p = __expf(row[e] - mx); row[e] = p; sum += p; }
    float inv = 1.f / sum;
    for (int e = 0; e < 64; ++e) row[e] *= inv;
  }
  __syncthreads();
  int jg = tid >> 4, eg = tid & 15;   // jg: 0..15 -> 8 j each; eg: 0..15 -> 4 e each
  int j0 = jg * 8;                    // within 128-col slice
  float a[4][8];
  for (int i = 0; i < 4; ++i)
    for (int j = 0; j < 8; ++j) a[i][j] = 0.f;
  for (int d = 0; d < 64; ++d) {
    fx4 at = *(const fx4*)&S[d * 64 + eg * 4];
    s16x8 wv = *(const s16x8*)&wps[d * 128 + j0];
    float wf[8];
    for (int j = 0; j < 8; ++j) wf[j] = bf2f((unsigned short)wv[j]);
    for (int i = 0; i < 4; ++i)
      for (int j = 0; j < 8; ++j) a[i][j] += at[i] * wf[j];
  }
  int jglob = jblk * 128 + j0;
  for (int j = 0; j < 8; ++j)
    for (int i = 0; i < 4; ++i)
      weffT[(((size_t)b * 512 + jglob + j) << 9) + h * 64 + eg * 4 + i] = f2bf(a[i][j]);
}

// ---------------- host ----------------
extern "C" void kernel_launch(void* const* d_in, const int* in_sizes, int n_in,
                              void* d_out, int out_size, void* d_ws, size_t ws_size,
                              hipStream_t stream) {
  const float* x      = (const float*)d_in[0];
  const float* w_qkv  = (const float*)d_in[1];
  const float* b_qkv  = (const float*)d_in[2];
  const float* w_p    = (const float*)d_in[3];
  const float* b_p    = (const float*)d_in[4];
  const float* temp   = (const float*)d_in[5];
  float* out = (float*)d_out;
  char* ws = (char*)d_ws;

  // workspace layout (xb region reused for sp/weffT after GEMM A)
  unsigned short* xb    = (unsigned short*)(ws + 0);          // 33,554,432 B
  float*          sp    = (float*)(ws + 0);                   //  8,388,608 B (after xb dead)
  unsigned short* weffT = (unsigned short*)(ws + 8388608);    //  4,194,304 B
  unsigned short* wqkvT = (unsigned short*)(ws + 33554432);   //  1,572,864 B
  unsigned short* wpb   = (unsigned short*)(ws + 35127296);   //    524,288 B
  unsigned short* qb    = (unsigned short*)(ws + 35651584);   // 33,554,432 B
  unsigned short* kb    = (unsigned short*)(ws + 69206016);   // 33,554,432 B
  unsigned short* vb    = (unsigned short*)(ws + 102760448);  // 33,554,432 B

  cast_x_k<<<8192, 256, 0, stream>>>(x, xb);
  twqkv_k<<<3072, 256, 0, stream>>>(w_qkv, wqkvT);
  cast_wp_k<<<1024, 256, 0, stream>>>(w_p, wpb);
  gemm_k<0><<<768, 512, 0, stream>>>(xb, wqkvT, b_qkv, qb, kb, vb, nullptr);
  scores_partial_k<<<512, 256, 0, stream>>>(qb, kb, sp);
  softmax_weff_k<<<256, 256, 0, stream>>>(sp, wpb, temp, weffT);
  gemm_k<1><<<256, 512, 0, stream>>>(vb, weffT, b_p, nullptr, nullptr, nullptr, out);
}

// Round 6
// 171.331 us; speedup vs baseline: 1.0680x; 1.0680x over previous
//
#include <hip/hip_runtime.h>

typedef __attribute__((ext_vector_type(8))) short s16x8;
typedef __attribute__((ext_vector_type(4))) short s16x4;
typedef __attribute__((ext_vector_type(4))) float fx4;

__device__ inline unsigned short f2bf(float f) {
  unsigned u = __float_as_uint(f);
  u += 0x7fffu + ((u >> 16) & 1u);
  return (unsigned short)(u >> 16);
}
__device__ inline float bf2f(unsigned short s) {
  return __uint_as_float(((unsigned)s) << 16);
}

#define GLDS16(gp, lp) \
  __builtin_amdgcn_global_load_lds((const __attribute__((address_space(1))) void*)(gp), \
                                   (__attribute__((address_space(3))) void*)(lp), 16, 0, 0)

// ---------------- cast / transpose kernels ----------------
__global__ __launch_bounds__(256) void cast_x_k(const float* __restrict__ x,
                                                unsigned short* __restrict__ xb) {
  int i = (blockIdx.x * 256 + threadIdx.x) * 8;
  fx4 a = *(const fx4*)&x[i];
  fx4 b = *(const fx4*)&x[i + 4];
  s16x8 o;
  o[0] = (short)f2bf(a[0]); o[1] = (short)f2bf(a[1]);
  o[2] = (short)f2bf(a[2]); o[3] = (short)f2bf(a[3]);
  o[4] = (short)f2bf(b[0]); o[5] = (short)f2bf(b[1]);
  o[6] = (short)f2bf(b[2]); o[7] = (short)f2bf(b[3]);
  *(s16x8*)&xb[i] = o;
}

__global__ __launch_bounds__(256) void twqkv_k(const float* __restrict__ w,
                                               unsigned short* __restrict__ wT) {
  int o = blockIdx.x * 256 + threadIdx.x;      // < 1536*512
  int j = o >> 9, kk = o & 511;
  wT[o] = f2bf(w[kk * 1536 + j]);
}

__global__ __launch_bounds__(256) void cast_wp_k(const float* __restrict__ w,
                                                 unsigned short* __restrict__ wb) {
  int o = blockIdx.x * 256 + threadIdx.x;      // < 512*512
  wb[o] = f2bf(w[o]);
}

// ---------------- GEMM: 128x128 tile, BK=32, 4 waves (2x2), 16x16x32 bf16 MFMA.
// Minimal 2-phase pipeline (catalog T3-minimum): per K-tile
//   STAGE(next tile -> other buf); ds_read cur; MFMA; vmcnt(0); ONE s_barrier.
// 32 KB LDS -> 4-5 blocks/CU: cross-block TLP hides the drain (m114).
// Chunk-XOR LDS swizzle (linear GLDS dest + pre-swizzled source + XOR read).
// MODE 0: A=[32768][512] xb, BT=[1536][512] wqkvT -> q,k,v (bf16 split layouts)
// MODE 1: A=v + bb*4096*512, BT=weffT + bb*512*512 -> fp32 [b n][512]
template <int MODE>
__global__ __launch_bounds__(256, 4) void gemm_k(
    const unsigned short* __restrict__ A, const unsigned short* __restrict__ BT,
    const float* __restrict__ bias,
    unsigned short* __restrict__ qo, unsigned short* __restrict__ ko,
    unsigned short* __restrict__ vo, float* __restrict__ outp) {
  __shared__ alignas(16) unsigned short As[2][128 * 32];
  __shared__ alignas(16) unsigned short Bs[2][128 * 32];
  int tid = threadIdx.x, wave = tid >> 6, lane = tid & 63;
  int l15 = lane & 15, l16 = lane >> 4;
  int wr = wave >> 1, wc = wave & 1;

  // XCD-aware bijective swizzle (nwg % 8 == 0 in both modes)
  int nwg = (MODE == 0) ? 3072 : 1024;
  int cpx = nwg >> 3;
  int bid = (blockIdx.x & 7) * cpx + (blockIdx.x >> 3);

  int mt, nt, bb = 0;
  if (MODE == 0) { mt = bid / 12; nt = bid % 12; }
  else { bb = bid >> 7; int r = bid & 127; mt = r >> 2; nt = r & 3; }
  const unsigned short* Ab = A + (MODE == 0 ? (size_t)0 : (size_t)bb * 4096 * 512);
  const unsigned short* Bb = BT + (MODE == 0 ? (size_t)0 : (size_t)bb * 512 * 512);
  int row0 = mt * 128, col0 = nt * 128;

  fx4 acc[4][4];
#pragma unroll
  for (int i = 0; i < 4; ++i)
#pragma unroll
    for (int j = 0; j < 4; ++j) acc[i][j] = (fx4){0.f, 0.f, 0.f, 0.f};

  // Staging: wave covers 16 rows per GLDS call (4 lanes x 16B per 64B row).
  // Source chunk pre-swizzled: lane loads global chunk (l&3)^g, g=(l>>3)&3,
  // so linear LDS dest stores chunk p of row R at slot p ^ g(R).
  int smr = wave * 16 + (lane >> 2);       // row within 64-row group
  int skk = (((lane & 3) ^ ((lane >> 3) & 3))) * 8;  // swizzled k-chunk offset
  const unsigned short* agp = Ab + (size_t)(row0 + smr) * 512 + skk;
  const unsigned short* bgp = Bb + (size_t)(col0 + smr) * 512 + skk;
  int ldsoff = wave * 512;                 // elements; 1024B per wave

#define STAGE(buf, kt_)                                        \
  do {                                                         \
    int k0_ = (kt_) * 32;                                      \
    GLDS16(agp + k0_, &As[buf][ldsoff]);                       \
    GLDS16(agp + 64 * 512 + k0_, &As[buf][ldsoff + 2048]);     \
    GLDS16(bgp + k0_, &Bs[buf][ldsoff]);                       \
    GLDS16(bgp + 64 * 512 + k0_, &Bs[buf][ldsoff + 2048]);     \
  } while (0)

  STAGE(0, 0);
  asm volatile("s_waitcnt vmcnt(0)" ::: "memory");
  __builtin_amdgcn_s_barrier();

  // read-side swizzle: chunk c of row R lives at slot c ^ g(R), g=(l15>>1)&3
  int g = (l15 >> 1) & 3;
  int pa = (l16 ^ g) << 3;                 // element offset of swizzled chunk

  for (int kt = 0; kt < 16; ++kt) {
    int cur = kt & 1;
    if (kt < 15) STAGE(cur ^ 1, kt + 1);   // issue next tile FIRST (overlaps below)

    s16x8 af[4], bf[4];
#pragma unroll
    for (int mi = 0; mi < 4; ++mi)
      af[mi] = *(const s16x8*)&As[cur][(wr * 64 + mi * 16 + l15) * 32 + pa];
#pragma unroll
    for (int nj = 0; nj < 4; ++nj)
      bf[nj] = *(const s16x8*)&Bs[cur][(wc * 64 + nj * 16 + l15) * 32 + pa];
#pragma unroll
    for (int mi = 0; mi < 4; ++mi)
#pragma unroll
      for (int nj = 0; nj < 4; ++nj)
        acc[mi][nj] = __builtin_amdgcn_mfma_f32_16x16x32_bf16(af[mi], bf[nj], acc[mi][nj], 0, 0, 0);

    // single drain + single barrier per K-tile: next buffer ready, this
    // buffer's reads (lgkm-waited before MFMA) done block-wide past here.
    asm volatile("s_waitcnt vmcnt(0)" ::: "memory");
    __builtin_amdgcn_s_barrier();
  }
#undef STAGE

  int crow0 = row0 + wr * 64;
  int ccol0 = col0 + wc * 64;
  if (MODE == 0) {
    int seg = ccol0 >> 9;  // 0=q,1=k,2=v (tile never spans segments)
#pragma unroll
    for (int mi = 0; mi < 4; ++mi)
#pragma unroll
      for (int nj = 0; nj < 4; ++nj) {
        int gc = ccol0 + nj * 16 + l15;
        float bsv = bias[gc];
#pragma unroll
        for (int r = 0; r < 4; ++r) {
          int gr = crow0 + mi * 16 + l16 * 4 + r;
          unsigned short o = f2bf(acc[mi][nj][r] + bsv);
          int b_ = gr >> 12, n_ = gr & 4095;
          if (seg == 0) {
            qo[((((size_t)b_ * 8 + (gc >> 6)) * 4096 + n_) << 6) + (gc & 63)] = o;
          } else if (seg == 1) {
            int c2 = gc - 512;
            ko[((((size_t)b_ * 8 + (c2 >> 6)) * 4096 + n_) << 6) + (c2 & 63)] = o;
          } else {
            vo[((size_t)gr << 9) + (gc - 1024)] = o;
          }
        }
      }
  } else {
#pragma unroll
    for (int mi = 0; mi < 4; ++mi)
#pragma unroll
      for (int nj = 0; nj < 4; ++nj) {
        int gc = ccol0 + nj * 16 + l15;
        float bsv = bias[gc];
#pragma unroll
        for (int r = 0; r < 4; ++r) {
          int gr = crow0 + mi * 16 + l16 * 4 + r;  // row within batch
          outp[(((size_t)bb * 4096 + gr) << 9) + gc] = acc[mi][nj][r] + bsv;
        }
      }
  }
}

// ---------------- partial scores: S_part[bh][seg][d][e] = sum_{n in seg} q[n][d]*k[n][e]
__global__ __launch_bounds__(256) void scores_partial_k(const unsigned short* __restrict__ q,
                                                        const unsigned short* __restrict__ k,
                                                        float* __restrict__ sp) {
  __shared__ alignas(16) float qs[64 * 64];
  __shared__ alignas(16) float ks[64 * 64];
  int bid = blockIdx.x;            // 512 = bh*8 + seg
  int bh = bid >> 3, seg = bid & 7;
  const unsigned short* qb = q + ((size_t)bh * 4096 + seg * 512) * 64;
  const unsigned short* kb = k + ((size_t)bh * 4096 + seg * 512) * 64;
  int tid = threadIdx.x;
  int dg = tid >> 4, eg = tid & 15;
  float acc[4][4] = {{0.f}};
  for (int ch = 0; ch < 8; ++ch) {
    __syncthreads();
    for (int r = 0; r < 4; ++r) {
      int idx = r * 1024 + tid * 4;
      s16x4 qv = *(const s16x4*)&qb[ch * 4096 + idx];
      s16x4 kv = *(const s16x4*)&kb[ch * 4096 + idx];
      fx4 qf = {bf2f((unsigned short)qv[0]), bf2f((unsigned short)qv[1]),
                bf2f((unsigned short)qv[2]), bf2f((unsigned short)qv[3])};
      fx4 kf = {bf2f((unsigned short)kv[0]), bf2f((unsigned short)kv[1]),
                bf2f((unsigned short)kv[2]), bf2f((unsigned short)kv[3])};
      *(fx4*)&qs[idx] = qf;
      *(fx4*)&ks[idx] = kf;
    }
    __syncthreads();
    for (int n = 0; n < 64; ++n) {
      fx4 qv4 = *(const fx4*)&qs[n * 64 + dg * 4];
      fx4 kv4 = *(const fx4*)&ks[n * 64 + eg * 4];
      for (int i = 0; i < 4; ++i)
        for (int j = 0; j < 4; ++j) acc[i][j] += qv4[i] * kv4[j];
    }
  }
  float* o = sp + (size_t)bid * 4096;
  for (int i = 0; i < 4; ++i)
    for (int j = 0; j < 4; ++j) o[(dg * 4 + i) * 64 + eg * 4 + j] = acc[i][j];
}

// ---------------- softmax + W_effT[b][j][h*64+e] = sum_d attn[d][e] * wp[h*64+d][j]
// grid 256: block = bh*4 + jblk, each handles 128 output j-columns
__global__ __launch_bounds__(256) void softmax_weff_k(const float* __restrict__ sp,
                                                      const unsigned short* __restrict__ wpb,
                                                      const float* __restrict__ temp,
                                                      unsigned short* __restrict__ weffT) {
  __shared__ alignas(16) float S[64 * 64];
  __shared__ alignas(16) unsigned short wps[64 * 128];
  int bh = blockIdx.x >> 2, jblk = blockIdx.x & 3;
  int b = bh >> 3, h = bh & 7;
  int tid = threadIdx.x;
  float tval = temp[h];
  for (int i = tid * 4; i < 4096; i += 1024) {
    fx4 s = {0.f, 0.f, 0.f, 0.f};
    for (int seg = 0; seg < 8; ++seg) {
      fx4 v4 = *(const fx4*)&sp[((size_t)(bh * 8 + seg)) * 4096 + i];
      s += v4;
    }
    s *= tval;
    *(fx4*)&S[i] = s;
  }
  // stage wp slice: rows h*64..h*64+63, cols jblk*128..+128
  for (int i = tid * 8; i < 8192; i += 2048) {
    int d = i >> 7, c = i & 127;
    *(s16x8*)&wps[i] = *(const s16x8*)&wpb[(size_t)(h * 64 + d) * 512 + jblk * 128 + c];
  }
  __syncthreads();
  if (tid < 64) {
    float* row = &S[tid * 64];
    float mx = row[0];
    for (int e = 1; e < 64; ++e) mx = fmaxf(mx, row[e]);
    float sum = 0.f;
    for (int e = 0; e < 64; ++e) { float p = __expf(row[e] - mx); row[e] = p; sum += p; }
    float inv = 1.f / sum;
    for (int e = 0; e < 64; ++e) row[e] *= inv;
  }
  __syncthreads();
  int jg = tid >> 4, eg = tid & 15;   // jg: 0..15 -> 8 j each; eg: 0..15 -> 4 e each
  int j0 = jg * 8;                    // within 128-col slice
  float a[4][8];
  for (int i = 0; i < 4; ++i)
    for (int j = 0; j < 8; ++j) a[i][j] = 0.f;
  for (int d = 0; d < 64; ++d) {
    fx4 at = *(const fx4*)&S[d * 64 + eg * 4];
    s16x8 wv = *(const s16x8*)&wps[d * 128 + j0];
    float wf[8];
    for (int j = 0; j < 8; ++j) wf[j] = bf2f((unsigned short)wv[j]);
    for (int i = 0; i < 4; ++i)
      for (int j = 0; j < 8; ++j) a[i][j] += at[i] * wf[j];
  }
  int jglob = jblk * 128 + j0;
  for (int j = 0; j < 8; ++j)
    for (int i = 0; i < 4; ++i)
      weffT[(((size_t)b * 512 + jglob + j) << 9) + h * 64 + eg * 4 + i] = f2bf(a[i][j]);
}

// ---------------- host ----------------
extern "C" void kernel_launch(void* const* d_in, const int* in_sizes, int n_in,
                              void* d_out, int out_size, void* d_ws, size_t ws_size,
                              hipStream_t stream) {
  const float* x      = (const float*)d_in[0];
  const float* w_qkv  = (const float*)d_in[1];
  const float* b_qkv  = (const float*)d_in[2];
  const float* w_p    = (const float*)d_in[3];
  const float* b_p    = (const float*)d_in[4];
  const float* temp   = (const float*)d_in[5];
  float* out = (float*)d_out;
  char* ws = (char*)d_ws;

  // workspace layout (xb region reused for sp/weffT after GEMM A)
  unsigned short* xb    = (unsigned short*)(ws + 0);          // 33,554,432 B
  float*          sp    = (float*)(ws + 0);                   //  8,388,608 B (after xb dead)
  unsigned short* weffT = (unsigned short*)(ws + 8388608);    //  4,194,304 B
  unsigned short* wqkvT = (unsigned short*)(ws + 33554432);   //  1,572,864 B
  unsigned short* wpb   = (unsigned short*)(ws + 35127296);   //    524,288 B
  unsigned short* qb    = (unsigned short*)(ws + 35651584);   // 33,554,432 B
  unsigned short* kb    = (unsigned short*)(ws + 69206016);   // 33,554,432 B
  unsigned short* vb    = (unsigned short*)(ws + 102760448);  // 33,554,432 B

  cast_x_k<<<8192, 256, 0, stream>>>(x, xb);
  twqkv_k<<<3072, 256, 0, stream>>>(w_qkv, wqkvT);
  cast_wp_k<<<1024, 256, 0, stream>>>(w_p, wpb);
  gemm_k<0><<<3072, 256, 0, stream>>>(xb, wqkvT, b_qkv, qb, kb, vb, nullptr);
  scores_partial_k<<<512, 256, 0, stream>>>(qb, kb, sp);
  softmax_weff_k<<<256, 256, 0, stream>>>(sp, wpb, temp, weffT);
  gemm_k<1><<<1024, 256, 0, stream>>>(vb, weffT, b_p, nullptr, nullptr, nullptr, out);
}